// Round 3
// baseline (114.695 us; speedup 1.0000x reference)
//
#include <hip/hip_runtime.h>
#include <math.h>

#define NELEM   262144            // 4*64*32*32
#define PIMG    1296              // 36*36 padded image stride per (b,pair)
#define PPADN   165888            // 4*32*36*36 words
#define NHALO   16896             // 128 images * 132 halo words
#define EPS_BN  1e-5f
#define QSC     128.0f
#define QBIAS_F 16384.5f          // bias 16384 + 0.5 rounding
#define QZ_W    0x40004000u       // packed quantized zero
#define QINV    (1.0f / 128.0f)

// v_sad_u16: acc += |a.lo-b.lo| + |a.hi-b.hi|  (two terms per instruction)
__device__ __forceinline__ unsigned sad16(unsigned a, unsigned b, unsigned acc) {
    asm("v_sad_u16 %0, %1, %2, %0" : "+v"(acc) : "v"(a), "v"(b));
    return acc;
}
__device__ __forceinline__ unsigned qu(float v) {
    return (unsigned)(int)fmaf(v, QSC, QBIAS_F);
}

// ---------------------------------------------------------------------------
// adder1: prep fused in. Grid 1024 = b(4) x og(32: 2 outs) x sp(8: 4-row
// strips); 256 threads, __launch_bounds__(256,4) -> 4 blocks/CU.
// Stages bn1+relu+quant(x) strip [32 pairs][6 rows][36 cols] into LDS,
// quantizes its own 2 channels of w1 inline, writes qout1p halo ring and
// zeroes sbuf, computes SADs, then quant(relu(bn2(-acc))) -> packed qout1p.
// LDS: xs (27648B, reused as red after a barrier) + wlds = 30720B total.
// ---------------------------------------------------------------------------
__global__ __launch_bounds__(256, 4) void adder1_kernel(
    const float* __restrict__ x,
    const float* __restrict__ g1, const float* __restrict__ b1,
    const float* __restrict__ m1, const float* __restrict__ v1,
    const float* __restrict__ w1,
    const float* __restrict__ g2, const float* __restrict__ b2,
    const float* __restrict__ m2, const float* __restrict__ v2,
    unsigned* __restrict__ qout, float* __restrict__ sbuf)
{
    __shared__ unsigned smem[7680];                  // 30720 B
    unsigned (*xs)[6][36]    = reinterpret_cast<unsigned(*)[6][36]>(smem);        // 6912 w
    unsigned (*red)[32][9]   = reinterpret_cast<unsigned(*)[32][9]>(smem);        // 2304 w (aliases xs)
    unsigned (*wlds)[32][12] = reinterpret_cast<unsigned(*)[32][12]>(smem + 6912);// 768 w

    const int blk = blockIdx.x;
    const int sp  = blk & 7;                 // rows [sp*4, sp*4+4)
    const int og  = (blk >> 3) & 31;
    const int b   = blk >> 8;
    const int t   = threadIdx.x;

    // ---- side duties: sbuf zero (block 0) + qout1p halo ring ----
    const int gid = blk * 256 + t;
    if (gid < 256) sbuf[gid] = 0.f;
    if (gid < NHALO) {
        int img = gid / 132;
        int j   = gid - img * 132;
        int r, c;
        if (j < 34)       { r = 0;          c = j;       }
        else if (j < 68)  { r = 33;         c = j - 34;  }
        else if (j < 100) { r = j - 68 + 1; c = 0;       }
        else              { r = j - 100 + 1; c = 33;     }
        qout[img * PIMG + r * 36 + c] = QZ_W;
    }

    // ---- weight staging: 2 o x 32 pairs x 9 words, quantized from w1 ----
    for (int i = t; i < 576; i += 256) {
        int o_i = i / 288;
        int rem = i - o_i * 288;
        int pr  = rem / 9;
        int kk  = rem - pr * 9;
        int woff = ((og * 2 + o_i) * 64 + pr * 2) * 9 + kk;
        wlds[o_i][pr][kk] = qu(w1[woff]) | (qu(w1[woff + 9]) << 16);
    }

    // ---- x-strip staging: 32 pairs x 6 padded rows x 36 cols ----
    for (int u = t; u < 192; u += 256) {
        const int pair = u / 6;
        const int lr   = u - pair * 6;               // local padded row 0..5
        const int xrow = sp * 4 + lr - 1;            // x row, -1..32
        unsigned* dst  = &xs[pair][lr][0];
        if (xrow < 0 || xrow > 31) {
#pragma unroll
            for (int k = 0; k < 9; ++k)
                reinterpret_cast<uint4*>(dst)[k] = make_uint4(QZ_W, QZ_W, QZ_W, QZ_W);
        } else {
            const int c0 = pair * 2;
            const float inv0 = g1[c0]     * rsqrtf(v1[c0]     + EPS_BN);
            const float bet0 = b1[c0]     - m1[c0]     * inv0;
            const float inv1 = g1[c0 + 1] * rsqrtf(v1[c0 + 1] + EPS_BN);
            const float bet1 = b1[c0 + 1] - m1[c0 + 1] * inv1;
            const float* x0p = x + ((b * 64 + c0) * 32 + xrow) * 32;
            const float* x1p = x0p + 1024;
#pragma unroll
            for (int k = 0; k < 9; ++k) {
                unsigned q[4];
#pragma unroll
                for (int e = 0; e < 4; ++e) {
                    int c = k * 4 + e;               // padded col 0..35
                    unsigned qv = QZ_W;
                    if (c >= 1 && c <= 32) {
                        float a0 = fmaxf(fmaf(x0p[c - 1], inv0, bet0), 0.f);
                        float a1 = fmaxf(fmaf(x1p[c - 1], inv1, bet1), 0.f);
                        qv = qu(a0) | (qu(a1) << 16);
                    }
                    q[e] = qv;
                }
                reinterpret_cast<uint4*>(dst)[k] = make_uint4(q[0], q[1], q[2], q[3]);
            }
        }
    }
    __syncthreads();

    // ---- SAD compute ----
    const int pos = t & 31;
    const int cq  = t >> 5;                  // 0..7, 4 pairs each
    const int y_i = pos >> 3;                // 0..3
    const int x0  = (pos & 7) * 4;           // 0..28

    unsigned acc[2][4];
#pragma unroll
    for (int oo = 0; oo < 2; ++oo)
#pragma unroll
        for (int xi = 0; xi < 4; ++xi) acc[oo][xi] = 0u;

#pragma unroll
    for (int j = 0; j < 4; ++j) {
        const int pr = cq * 4 + j;
        unsigned p[3][6];
#pragma unroll
        for (int r = 0; r < 3; ++r) {
            const unsigned* src = &xs[pr][y_i + r][x0];
            uint4 a0 = *reinterpret_cast<const uint4*>(src);
            uint2 a1 = *reinterpret_cast<const uint2*>(src + 4);
            p[r][0] = a0.x; p[r][1] = a0.y; p[r][2] = a0.z; p[r][3] = a0.w;
            p[r][4] = a1.x; p[r][5] = a1.y;
        }
#pragma unroll
        for (int oo = 0; oo < 2; ++oo) {
            uint4 wa = *reinterpret_cast<const uint4*>(&wlds[oo][pr][0]);
            uint4 wb = *reinterpret_cast<const uint4*>(&wlds[oo][pr][4]);
            unsigned w8 = wlds[oo][pr][8];
            unsigned wv[9] = {wa.x, wa.y, wa.z, wa.w,
                              wb.x, wb.y, wb.z, wb.w, w8};
#pragma unroll
            for (int kh = 0; kh < 3; ++kh)
#pragma unroll
                for (int kw = 0; kw < 3; ++kw) {
                    unsigned ww = wv[kh * 3 + kw];
#pragma unroll
                    for (int xi = 0; xi < 4; ++xi)
                        acc[oo][xi] = sad16(p[kh][xi + kw], ww, acc[oo][xi]);
                }
        }
    }
    __syncthreads();                          // xs reads done before red aliases it

    // ---- cq reduction via LDS (stride-9: conflict-free writes) ----
    {
        unsigned* dst = &red[cq][pos][0];
#pragma unroll
        for (int z = 0; z < 8; ++z) dst[z] = acc[z >> 2][z & 3];
    }
    __syncthreads();

    // 256 outputs: 2 o x 4 rows x 32 cols — every thread produces one
    const int oo2 = t >> 7;
    const int yy2 = (t >> 5) & 3;
    const int xx2 = t & 31;
    const int pp  = yy2 * 8 + (xx2 >> 2);
    const int z   = oo2 * 4 + (xx2 & 3);
    unsigned total = 0;
#pragma unroll
    for (int q = 0; q < 8; ++q) total += red[q][pp][z];

    const int o  = og * 2 + oo2;             // wave-uniform
    const int gy = sp * 4 + yy2;

    // bn2 consts inline (wave-uniform o -> broadcast loads)
    float inv = g2[o] * rsqrtf(v2[o] + EPS_BN);
    float cc0 = -inv * QINV;
    float cc1 = b2[o] - m2[o] * inv;
    float a2  = fmaxf(fmaf((float)total, cc0, cc1), 0.f);
    unsigned short qv = (unsigned short)(int)fmaf(a2, QSC, QBIAS_F);
    size_t widx = (size_t)(b * 32 + (o >> 1)) * PIMG + (gy + 1) * 36 + (xx2 + 1);
    reinterpret_cast<unsigned short*>(qout)[widx * 2 + (o & 1)] = qv;
}

// ---------------------------------------------------------------------------
// adder2: layer-2 SAD from packed qout1p; w2 quantized inline. Writes float
// out2 + SE spatial-sum atomics into sbuf. Same tiling as adder1.
// ---------------------------------------------------------------------------
__global__ __launch_bounds__(256, 4) void adder2_kernel(
    const unsigned* __restrict__ qsrc, const float* __restrict__ w2,
    float* __restrict__ fout, float* __restrict__ sbuf)
{
    __shared__ unsigned wlds[2][32][12];     // 3072 B
    __shared__ unsigned red[8][32][9];       // 9216 B

    const int blk = blockIdx.x;
    const int sp  = blk & 7;
    const int og  = (blk >> 3) & 31;
    const int b   = blk >> 8;
    const int t   = threadIdx.x;
    const int pos = t & 31;
    const int cq  = t >> 5;
    const int y_i = pos >> 3;
    const int x0  = (pos & 7) * 4;

    for (int i = t; i < 576; i += 256) {
        int o_i = i / 288;
        int rem = i - o_i * 288;
        int pr  = rem / 9;
        int kk  = rem - pr * 9;
        int woff = ((og * 2 + o_i) * 64 + pr * 2) * 9 + kk;
        wlds[o_i][pr][kk] = qu(w2[woff]) | (qu(w2[woff + 9]) << 16);
    }
    __syncthreads();

    unsigned acc[2][4];
#pragma unroll
    for (int oo = 0; oo < 2; ++oo)
#pragma unroll
        for (int xi = 0; xi < 4; ++xi) acc[oo][xi] = 0u;

#pragma unroll
    for (int j = 0; j < 4; ++j) {
        const int pr = cq * 4 + j;
        const unsigned* pc = qsrc + (size_t)(b * 32 + pr) * PIMG
                                  + (sp * 4 + y_i) * 36 + x0;
        unsigned p[3][6];
#pragma unroll
        for (int r = 0; r < 3; ++r) {
            uint4 a0 = *reinterpret_cast<const uint4*>(pc + r * 36);
            uint2 a1 = *reinterpret_cast<const uint2*>(pc + r * 36 + 4);
            p[r][0] = a0.x; p[r][1] = a0.y; p[r][2] = a0.z; p[r][3] = a0.w;
            p[r][4] = a1.x; p[r][5] = a1.y;
        }
#pragma unroll
        for (int oo = 0; oo < 2; ++oo) {
            uint4 wa = *reinterpret_cast<const uint4*>(&wlds[oo][pr][0]);
            uint4 wb = *reinterpret_cast<const uint4*>(&wlds[oo][pr][4]);
            unsigned w8 = wlds[oo][pr][8];
            unsigned wv[9] = {wa.x, wa.y, wa.z, wa.w,
                              wb.x, wb.y, wb.z, wb.w, w8};
#pragma unroll
            for (int kh = 0; kh < 3; ++kh)
#pragma unroll
                for (int kw = 0; kw < 3; ++kw) {
                    unsigned ww = wv[kh * 3 + kw];
#pragma unroll
                    for (int xi = 0; xi < 4; ++xi)
                        acc[oo][xi] = sad16(p[kh][xi + kw], ww, acc[oo][xi]);
                }
        }
    }

    {
        unsigned* dst = &red[cq][pos][0];
#pragma unroll
        for (int z = 0; z < 8; ++z) dst[z] = acc[z >> 2][z & 3];
    }
    __syncthreads();

    const int oo2 = t >> 7;
    const int yy2 = (t >> 5) & 3;
    const int xx2 = t & 31;
    const int pp  = yy2 * 8 + (xx2 >> 2);
    const int z   = oo2 * 4 + (xx2 & 3);
    unsigned total = 0;
#pragma unroll
    for (int q = 0; q < 8; ++q) total += red[q][pp][z];

    const int o  = og * 2 + oo2;
    const int gy = sp * 4 + yy2;

    float v = -(float)total * QINV;
    fout[((b * 64 + o) * 32 + gy) * 32 + xx2] = v;
    float sum = v;
#pragma unroll
    for (int off = 32; off > 0; off >>= 1)
        sum += __shfl_down(sum, off, 64);
    if ((t & 63) == 0) atomicAdd(&sbuf[b * 64 + o], sum);
}

// ---------------------------------------------------------------------------
// SE gate + apply + shortcut. 256 blocks (one per b,o image) x 256 threads.
// ---------------------------------------------------------------------------
__global__ __launch_bounds__(256) void gate_kernel(
    const float* __restrict__ out2, const float* __restrict__ x,
    const float* __restrict__ sbuf,
    const float* __restrict__ fc1w, const float* __restrict__ fc1b,
    const float* __restrict__ fc2w, const float* __restrict__ fc2b,
    float* __restrict__ out)
{
    const int bo = blockIdx.x;
    const int b  = bo >> 6;
    const int o  = bo & 63;
    const int t  = threadIdx.x;

    __shared__ float ss[64];
    if (t < 64) ss[t] = sbuf[b * 64 + t] * (1.f / 1024.f);
    __syncthreads();

    float h[4];
#pragma unroll
    for (int j = 0; j < 4; ++j) {
        float a = fc1b[j];
#pragma unroll
        for (int c = 0; c < 64; ++c) a += ss[c] * fc1w[j * 64 + c];
        h[j] = fmaxf(a, 0.f);
    }
    float zz = fc2b[o];
#pragma unroll
    for (int j = 0; j < 4; ++j) zz += h[j] * fc2w[o * 4 + j];
    float g = 1.f / (1.f + __expf(-zz));

    const int base = bo * 1024 + t * 4;
    float4 v  = *reinterpret_cast<const float4*>(out2 + base);
    float4 xv = *reinterpret_cast<const float4*>(x + base);
    float4 r;
    r.x = v.x * g + xv.x;
    r.y = v.y * g + xv.y;
    r.z = v.z * g + xv.z;
    r.w = v.w * g + xv.w;
    *reinterpret_cast<float4*>(out + base) = r;
}

// ---------------------------------------------------------------------------
extern "C" void kernel_launch(void* const* d_in, const int* in_sizes, int n_in,
                              void* d_out, int out_size, void* d_ws, size_t ws_size,
                              hipStream_t stream)
{
    const float* x    = (const float*)d_in[0];
    const float* bn1g = (const float*)d_in[1];
    const float* bn1b = (const float*)d_in[2];
    const float* bn1m = (const float*)d_in[3];
    const float* bn1v = (const float*)d_in[4];
    const float* w1   = (const float*)d_in[5];
    const float* bn2g = (const float*)d_in[6];
    const float* bn2b = (const float*)d_in[7];
    const float* bn2m = (const float*)d_in[8];
    const float* bn2v = (const float*)d_in[9];
    const float* w2   = (const float*)d_in[10];
    const float* fc1w = (const float*)d_in[11];
    const float* fc1b = (const float*)d_in[12];
    const float* fc2w = (const float*)d_in[13];
    const float* fc2b = (const float*)d_in[14];

    unsigned* ws     = (unsigned*)d_ws;
    unsigned* qout1p = ws;                              // PPADN
    float*    out2   = (float*)(ws + PPADN);            // NELEM
    float*    sbuf   = (float*)(ws + PPADN + NELEM);    // 256

    adder1_kernel<<<1024, 256, 0, stream>>>(x, bn1g, bn1b, bn1m, bn1v, w1,
                                            bn2g, bn2b, bn2m, bn2v,
                                            qout1p, sbuf);
    adder2_kernel<<<1024, 256, 0, stream>>>(qout1p, w2, out2, sbuf);
    gate_kernel<<<256, 256, 0, stream>>>(out2, x, sbuf, fc1w, fc1b, fc2w, fc2b,
                                         (float*)d_out);
}